// Round 3
// baseline (45.587 us; speedup 1.0000x reference)
//
#include <hip/hip_runtime.h>
#include <math.h>

#define BB 4
#define NN 2048
#define MM 128
#define DD 64
#define NEG_SLOPE 0.2f

#define MT 16                 // m per fused block
#define NMT (MM / MT)         // 8 m-tiles
#define NSPL 16               // n splits
#define NR (NN / NSPL)        // 128 n per block
#define NCH 16                // n per chunk
#define NIT (NR / NCH)        // 8 iters

// ---------------------------------------------------------------------------
// proj_all: blocks 0..511  : hs[row,d] = fs[row,:].W_src[d,:]; el[row]=hs.attn_l
//           blocks 512,513 : er[i] = fd[i,:].u_r  (u_r = attn_r @ W_dst)
//                            block 512 also writes c_e = W_edge . attn_e
// ---------------------------------------------------------------------------
__global__ __launch_bounds__(256) void proj_all_kernel(
        const float* __restrict__ fs, const float* __restrict__ W_src,
        const float* __restrict__ attn_l,
        const float* __restrict__ fd, const float* __restrict__ W_dst,
        const float* __restrict__ attn_r,
        const float* __restrict__ W_edge, const float* __restrict__ attn_e,
        float* __restrict__ hs, float* __restrict__ el,
        float* __restrict__ er, float* __restrict__ c_e) {
    int t = threadIdx.x;
    if (blockIdx.x < 512) {
        int lane = t & 63, w = t >> 6;
        int row0 = blockIdx.x * 16;
        __shared__ float4 rows4[16][16];
        const float4* fs4 = (const float4*)(fs + (size_t)row0 * DD);
        ((float4*)rows4)[t] = fs4[t];
        float4 wreg[16];
        const float4* w4 = (const float4*)(W_src + (size_t)lane * DD);
#pragma unroll
        for (int k = 0; k < 16; ++k) wreg[k] = w4[k];
        float al = attn_l[lane];
        __syncthreads();
        float acc[4] = {0.f, 0.f, 0.f, 0.f};
#pragma unroll
        for (int k = 0; k < 16; ++k) {
#pragma unroll
            for (int j = 0; j < 4; ++j) {
                float4 rv = rows4[w * 4 + j][k];
                acc[j] += rv.x * wreg[k].x + rv.y * wreg[k].y +
                          rv.z * wreg[k].z + rv.w * wreg[k].w;
            }
        }
#pragma unroll
        for (int j = 0; j < 4; ++j) {
            int row = row0 + w * 4 + j;
            hs[(size_t)row * DD + lane] = acc[j];
            float v = acc[j] * al;
            for (int off = 32; off > 0; off >>= 1) v += __shfl_xor(v, off, 64);
            if (lane == 0) el[row] = v;
        }
    } else {
        int eb = blockIdx.x - 512;
        __shared__ float u_r[DD];
        if (t < DD) {
            float a = 0.f;
            for (int d = 0; d < DD; ++d) a += attn_r[d] * W_dst[d * DD + t];
            u_r[t] = a;
        }
        if (eb == 0 && t < 64) {
            float v = W_edge[t] * attn_e[t];
            for (int off = 32; off > 0; off >>= 1) v += __shfl_xor(v, off, 64);
            if (t == 0) *c_e = v;
        }
        __syncthreads();
        int i = eb * 256 + t;
        float acc = 0.f;
        const float4* fd4 = (const float4*)(fd + (size_t)i * DD);
        const float4* ur4 = (const float4*)u_r;
#pragma unroll
        for (int k = 0; k < 16; ++k) {
            float4 f = fd4[k], u = ur4[k];
            acc += f.x * u.x + f.y * u.y + f.z * u.z + f.w * u.w;
        }
        er[i] = acc;
    }
}

// ---------------------------------------------------------------------------
// fused: per (ns, mt, b) block: single-pass masked-softmax-weighted aggregation
// over its n-range (no max pass; scores bounded).  Writes partial
// pacc[b][mt][ns][m][d], pdn[b][mt][ns][m][{denom,sfe}].
// ---------------------------------------------------------------------------
__global__ __launch_bounds__(256) void fused_attn_kernel(
        const float* __restrict__ fe, const int* __restrict__ adj,
        const float* __restrict__ hs, const float* __restrict__ el,
        const float* __restrict__ er, const float* __restrict__ c_e_p,
        float* __restrict__ pacc, float* __restrict__ pdn) {
    int ns = blockIdx.x, mt = blockIdx.y, b = blockIdx.z;
    int n0 = ns * NR, m0 = mt * MT;
    int t = threadIdx.x;
    int m = t & 15, nh = t >> 4;          // score: (m, n=nh); agg: (m, dgrp=nh)

    __shared__ float p_lds[2][MT][NCH + 1];
    __shared__ float hs_lds[2][NCH][DD];
    __shared__ float el_lds[NR];
    __shared__ float dred[16][17], fred[16][17];

    if (t < NR) el_lds[t] = el[b * NN + n0 + t];
    float c_e = *c_e_p;
    float er_m = er[b * MM + m0 + m];
    __syncthreads();

    const float* fe_base = fe + ((size_t)(b * NN + n0)) * MM + m0;
    const int* adj_base = adj + ((size_t)(b * NN + n0)) * MM + m0;
    const float* hs_base = hs + ((size_t)(b * NN + n0)) * DD;

    float dsum = 0.f, fsum = 0.f;
    float acc[4] = {0.f, 0.f, 0.f, 0.f};

    for (int it = 0; it < NIT; ++it) {
        int buf = it & 1;
        int n = it * NCH + nh;
        float f = fe_base[(size_t)n * MM + m];
        int a = adj_base[(size_t)n * MM + m];
        float s = el_lds[n] + c_e * f + er_m;
        s = s > 0.f ? s : NEG_SLOPE * s;
        float p = (a == 1) ? __expf(s) : 0.f;
        p_lds[buf][m][nh] = p;
        dsum += p;
        fsum += f * p;
        ((float4*)hs_lds[buf])[t] =
            ((const float4*)(hs_base + (size_t)it * NCH * DD))[t];
        __syncthreads();
#pragma unroll
        for (int nn = 0; nn < NCH; ++nn) {
            float p2 = p_lds[buf][m][nn];
            float4 h = *(const float4*)(&hs_lds[buf][nn][nh * 4]);
            acc[0] += p2 * h.x;
            acc[1] += p2 * h.y;
            acc[2] += p2 * h.z;
            acc[3] += p2 * h.w;
        }
    }
    dred[nh][m] = dsum;
    fred[nh][m] = fsum;
    // partial acc write: (b,mt,ns,m, d=nh*4..)
    size_t pbase = (((size_t)(b * NMT + mt) * NSPL + ns) * MT + m);
    *(float4*)(pacc + pbase * DD + nh * 4) = *(float4*)acc;
    __syncthreads();
    if (t < MT) {
        float ds = 0.f, fs2 = 0.f;
#pragma unroll
        for (int k = 0; k < 16; ++k) { ds += dred[k][t]; fs2 += fred[k][t]; }
        size_t q = (((size_t)(b * NMT + mt) * NSPL + ns) * MT + t) * 2;
        pdn[q] = ds;
        pdn[q + 1] = fs2;
    }
}

// ---------------------------------------------------------------------------
// reduce: out[bm,d] = sigmoid((W_edge[d]*Σsfe + Σacc) / Σdenom)
// ---------------------------------------------------------------------------
__global__ __launch_bounds__(256) void reduce_kernel(
        const float* __restrict__ pacc, const float* __restrict__ pdn,
        const float* __restrict__ W_edge, float* __restrict__ out) {
    int gid = blockIdx.x * 256 + threadIdx.x;   // 32768
    int d = gid & 63, bm = gid >> 6;
    int b = bm >> 7, mm = bm & 127;
    int mt = mm >> 4, ml = mm & 15;
    size_t base = ((size_t)(b * NMT + mt)) * NSPL;
    float accs = 0.f, dens = 0.f, sfes = 0.f;
#pragma unroll
    for (int ns = 0; ns < NSPL; ++ns) {
        size_t idx = (base + ns) * MT + ml;
        accs += pacc[idx * DD + d];
        dens += pdn[idx * 2];
        sfes += pdn[idx * 2 + 1];
    }
    float v = (W_edge[d] * sfes + accs) / dens;
    out[(size_t)bm * DD + d] = 1.f / (1.f + __expf(-v));
}

extern "C" void kernel_launch(void* const* d_in, const int* in_sizes, int n_in,
                              void* d_out, int out_size, void* d_ws, size_t ws_size,
                              hipStream_t stream) {
    const float* feat_src  = (const float*)d_in[0];
    const float* feat_dst  = (const float*)d_in[1];
    const float* feat_edge = (const float*)d_in[2];
    const int*   adj       = (const int*)d_in[3];
    const float* W_src     = (const float*)d_in[4];
    const float* W_dst     = (const float*)d_in[5];
    const float* W_edge    = (const float*)d_in[6];
    const float* attn_l    = (const float*)d_in[7];
    const float* attn_r    = (const float*)d_in[8];
    const float* attn_e    = (const float*)d_in[9];
    float* out = (float*)d_out;

    float* ws   = (float*)d_ws;
    float* hs   = ws;                           // B*N*D = 524288
    float* el   = hs + (size_t)BB * NN * DD;    // 8192
    float* er   = el + BB * NN;                 // 512
    float* c_e  = er + BB * MM;                 // 1 (pad 64)
    float* pacc = c_e + 64;                     // B*NMT*NSPL*MT*DD = 524288
    float* pdn  = pacc + (size_t)BB * NMT * NSPL * MT * DD;  // 16384

    proj_all_kernel<<<514, 256, 0, stream>>>(feat_src, W_src, attn_l,
                                             feat_dst, W_dst, attn_r,
                                             W_edge, attn_e, hs, el, er, c_e);
    fused_attn_kernel<<<dim3(NSPL, NMT, BB), 256, 0, stream>>>(
        feat_edge, adj, hs, el, er, c_e, pacc, pdn);
    reduce_kernel<<<128, 256, 0, stream>>>(pacc, pdn, W_edge, out);
}

// Round 4
// 28.272 us; speedup vs baseline: 1.6125x; 1.6125x over previous
//
#include <hip/hip_runtime.h>
#include <math.h>

#define BB 4
#define NN 2048
#define MM 128
#define DD 64
#define NEG_SLOPE 0.2f

#define MT 16                 // m per fused block
#define NMT (MM / MT)         // 8 m-tiles
#define NSPL 16               // n splits
#define NR (NN / NSPL)        // 128 n per block

// ---------------------------------------------------------------------------
// proj_all: blocks 0..511  : hs[row,d] = fs[row,:].W_src[d,:]; el[row]=hs.attn_l
//           blocks 512,513 : er[i] = fd[i,:].u_r  (u_r = attn_r @ W_dst)
//                            block 512 also writes c_e = W_edge . attn_e
// ---------------------------------------------------------------------------
__global__ __launch_bounds__(256) void proj_all_kernel(
        const float* __restrict__ fs, const float* __restrict__ W_src,
        const float* __restrict__ attn_l,
        const float* __restrict__ fd, const float* __restrict__ W_dst,
        const float* __restrict__ attn_r,
        const float* __restrict__ W_edge, const float* __restrict__ attn_e,
        float* __restrict__ hs, float* __restrict__ el,
        float* __restrict__ er, float* __restrict__ c_e) {
    int t = threadIdx.x;
    if (blockIdx.x < 512) {
        int lane = t & 63, w = t >> 6;
        int row0 = blockIdx.x * 16;
        __shared__ float4 rows4[16][16];
        const float4* fs4 = (const float4*)(fs + (size_t)row0 * DD);
        ((float4*)rows4)[t] = fs4[t];
        float4 wreg[16];
        const float4* w4 = (const float4*)(W_src + (size_t)lane * DD);
#pragma unroll
        for (int k = 0; k < 16; ++k) wreg[k] = w4[k];
        float al = attn_l[lane];
        __syncthreads();
        float acc[4] = {0.f, 0.f, 0.f, 0.f};
#pragma unroll
        for (int k = 0; k < 16; ++k) {
#pragma unroll
            for (int j = 0; j < 4; ++j) {
                float4 rv = rows4[w * 4 + j][k];
                acc[j] += rv.x * wreg[k].x + rv.y * wreg[k].y +
                          rv.z * wreg[k].z + rv.w * wreg[k].w;
            }
        }
#pragma unroll
        for (int j = 0; j < 4; ++j) {
            int row = row0 + w * 4 + j;
            hs[(size_t)row * DD + lane] = acc[j];
            float v = acc[j] * al;
            for (int off = 32; off > 0; off >>= 1) v += __shfl_xor(v, off, 64);
            if (lane == 0) el[row] = v;
        }
    } else {
        int eb = blockIdx.x - 512;
        __shared__ float u_r[DD];
        if (t < DD) {
            float a = 0.f;
            for (int d = 0; d < DD; ++d) a += attn_r[d] * W_dst[d * DD + t];
            u_r[t] = a;
        }
        if (eb == 0 && t < 64) {
            float v = W_edge[t] * attn_e[t];
            for (int off = 32; off > 0; off >>= 1) v += __shfl_xor(v, off, 64);
            if (t == 0) *c_e = v;
        }
        __syncthreads();
        int i = eb * 256 + t;
        float acc = 0.f;
        const float4* fd4 = (const float4*)(fd + (size_t)i * DD);
        const float4* ur4 = (const float4*)u_r;
#pragma unroll
        for (int k = 0; k < 16; ++k) {
            float4 f = fd4[k], u = ur4[k];
            acc += f.x * u.x + f.y * u.y + f.z * u.z + f.w * u.w;
        }
        er[i] = acc;
    }
}

// ---------------------------------------------------------------------------
// fused: per (ns, mt, b): stage hs chunk (32KB), compute masked-leaky scores
// with coalesced fe/adj reads, p=exp(s) (no max pass; scores bounded), then
// partial aggregation acc[m][d] = sum_n p*hs.  Single __syncthreads.
// Writes pacc[b][mt][ns][m][d], pdn[b][mt][ns][m][{denom,sfe}].
// ---------------------------------------------------------------------------
__global__ __launch_bounds__(256, 4) void fused_attn_kernel(
        const float* __restrict__ fe, const int* __restrict__ adj,
        const float* __restrict__ hs, const float* __restrict__ el,
        const float* __restrict__ er, const float* __restrict__ c_e_p,
        float* __restrict__ pacc, float* __restrict__ pdn) {
    int ns = blockIdx.x, mt = blockIdx.y, b = blockIdx.z;
    int n0 = ns * NR, m0 = mt * MT;
    int t = threadIdx.x;

    __shared__ float hs_lds[NR][DD];       // 32 KB
    __shared__ float p_lds[MT][NR + 4];    // rows 16B-aligned (132*4=528)
    __shared__ float dred[16][17], fred[16][17];

    // stage hs chunk: 2048 float4, 8 per thread, contiguous
    const float4* hs4 = (const float4*)(hs + ((size_t)(b * NN + n0)) * DD);
#pragma unroll 4
    for (int k = 0; k < 8; ++k)
        ((float4*)hs_lds)[t + k * 256] = hs4[t + k * 256];

    // scores: thread (m = t&15, h = t>>4) does n = h + 16j
    int m = t & 15, h = t >> 4;
    float c_e = *c_e_p;
    float er_m = er[b * MM + m0 + m];
    const float* fe_p = fe + ((size_t)(b * NN + n0)) * MM + m0 + m;
    const int* adj_p = adj + ((size_t)(b * NN + n0)) * MM + m0 + m;
    const float* el_p = el + b * NN + n0;
    float dsum = 0.f, fsum = 0.f;
#pragma unroll 4
    for (int j = 0; j < 8; ++j) {
        int n = h + j * 16;
        float f = fe_p[(size_t)n * MM];
        int a = adj_p[(size_t)n * MM];
        float s = el_p[n] + c_e * f + er_m;
        s = s > 0.f ? s : NEG_SLOPE * s;
        float p = (a == 1) ? __expf(s) : 0.f;
        p_lds[m][n] = p;
        dsum += p;
        fsum += f * p;
    }
    dred[h][m] = dsum;
    fred[h][m] = fsum;
    __syncthreads();

    // aggregation: thread (d = t&63, wave g = t>>6) accumulates m = g*4+j
    int d = t & 63, g = t >> 6;
    float acc[4] = {0.f, 0.f, 0.f, 0.f};
    for (int n4 = 0; n4 < NR / 4; ++n4) {
        float h0 = hs_lds[n4 * 4 + 0][d];
        float h1 = hs_lds[n4 * 4 + 1][d];
        float h2 = hs_lds[n4 * 4 + 2][d];
        float h3 = hs_lds[n4 * 4 + 3][d];
#pragma unroll
        for (int j = 0; j < 4; ++j) {
            float4 p = *(const float4*)&p_lds[g * 4 + j][n4 * 4];
            acc[j] += p.x * h0 + p.y * h1 + p.z * h2 + p.w * h3;
        }
    }
    size_t pbase = (size_t)((b * NMT + mt) * NSPL + ns) * MT;
#pragma unroll
    for (int j = 0; j < 4; ++j)
        pacc[(pbase + g * 4 + j) * DD + d] = acc[j];

    if (t < MT) {
        float ds = 0.f, fs2 = 0.f;
#pragma unroll
        for (int k = 0; k < 16; ++k) { ds += dred[k][t]; fs2 += fred[k][t]; }
        size_t q = (pbase + t) * 2;
        pdn[q] = ds;
        pdn[q + 1] = fs2;
    }
}

// ---------------------------------------------------------------------------
// reduce: out[bm,d] = sigmoid((W_edge[d]*Σsfe + Σacc) / Σdenom)
// ---------------------------------------------------------------------------
__global__ __launch_bounds__(256) void reduce_kernel(
        const float* __restrict__ pacc, const float* __restrict__ pdn,
        const float* __restrict__ W_edge, float* __restrict__ out) {
    int gid = blockIdx.x * 256 + threadIdx.x;   // 32768
    int d = gid & 63, bm = gid >> 6;
    int b = bm >> 7, mm = bm & 127;
    int mt = mm >> 4, ml = mm & 15;
    size_t base = ((size_t)(b * NMT + mt)) * NSPL;
    float accs = 0.f, dens = 0.f, sfes = 0.f;
#pragma unroll
    for (int ns = 0; ns < NSPL; ++ns) {
        size_t idx = (base + ns) * MT + ml;
        accs += pacc[idx * DD + d];
        dens += pdn[idx * 2];
        sfes += pdn[idx * 2 + 1];
    }
    float v = (W_edge[d] * sfes + accs) / dens;
    out[(size_t)bm * DD + d] = 1.f / (1.f + __expf(-v));
}

extern "C" void kernel_launch(void* const* d_in, const int* in_sizes, int n_in,
                              void* d_out, int out_size, void* d_ws, size_t ws_size,
                              hipStream_t stream) {
    const float* feat_src  = (const float*)d_in[0];
    const float* feat_dst  = (const float*)d_in[1];
    const float* feat_edge = (const float*)d_in[2];
    const int*   adj       = (const int*)d_in[3];
    const float* W_src     = (const float*)d_in[4];
    const float* W_dst     = (const float*)d_in[5];
    const float* W_edge    = (const float*)d_in[6];
    const float* attn_l    = (const float*)d_in[7];
    const float* attn_r    = (const float*)d_in[8];
    const float* attn_e    = (const float*)d_in[9];
    float* out = (float*)d_out;

    float* ws   = (float*)d_ws;
    float* hs   = ws;                           // B*N*D = 524288
    float* el   = hs + (size_t)BB * NN * DD;    // 8192
    float* er   = el + BB * NN;                 // 512
    float* c_e  = er + BB * MM;                 // 1 (pad 64)
    float* pacc = c_e + 64;                     // B*NMT*NSPL*MT*DD = 524288
    float* pdn  = pacc + (size_t)BB * NMT * NSPL * MT * DD;  // 16384

    proj_all_kernel<<<514, 256, 0, stream>>>(feat_src, W_src, attn_l,
                                             feat_dst, W_dst, attn_r,
                                             W_edge, attn_e, hs, el, er, c_e);
    fused_attn_kernel<<<dim3(NSPL, NMT, BB), 256, 0, stream>>>(
        feat_edge, adj, hs, el, er, c_e, pacc, pdn);
    reduce_kernel<<<128, 256, 0, stream>>>(pacc, pdn, W_edge, out);
}